// Round 4
// baseline (2981559.961 us; speedup 1.0000x reference)
//
#include <hip/hip_runtime.h>
#include <math.h>

// B=16, T=512, F=512, H=8, D=64; rows = B*T = 8192
#define GRID_WGS 128   // launched WGs for GRU; 8 elected (same XCD) participate

typedef __attribute__((ext_vector_type(8))) short bf16x8;
typedef __attribute__((ext_vector_type(4))) float f32x4;
typedef __attribute__((ext_vector_type(4))) unsigned short us4;

static __device__ __forceinline__ float sigmoidf_(float x) {
    return 1.0f / (1.0f + __expf(-x));
}
static __device__ __forceinline__ unsigned short f2bf(float f) {
    unsigned int u = __float_as_uint(f);
    u += 0x7fffu + ((u >> 16) & 1u);
    return (unsigned short)(u >> 16);
}
static __device__ __forceinline__ void gload_lds16(const void* g, void* l) {
    __builtin_amdgcn_global_load_lds(
        (const __attribute__((address_space(1))) unsigned int*)g,
        (__attribute__((address_space(3))) unsigned int*)l, 16, 0, 0);
}

// ---------------- fp32 -> bf16 convert --------------------------------------------------------
__global__ __launch_bounds__(256)
void f2bf_kernel(const float* __restrict__ in, unsigned short* __restrict__ out)
{
    const int i = (blockIdx.x * 256 + threadIdx.x) * 4;
    const float4 v = *(const float4*)(in + i);
    const us4 o = {f2bf(v.x), f2bf(v.y), f2bf(v.z), f2bf(v.w)};
    *(us4*)(out + i) = o;
}

// ---------------- transpose+convert: in [K][N] f32 -> out [N][K] bf16 -------------------------
__global__ __launch_bounds__(256)
void transpose_bf16(const float* __restrict__ in, unsigned short* __restrict__ out,
                    int K, int N)
{
    __shared__ float tile[32][33];
    const int n0 = blockIdx.x * 32, k0 = blockIdx.y * 32;
    const int c = threadIdx.x & 31, r8 = threadIdx.x >> 5;
#pragma unroll
    for (int i = 0; i < 4; ++i) {
        const int k = r8 + i * 8;
        tile[k][c] = in[(size_t)(k0 + k) * N + n0 + c];
    }
    __syncthreads();
#pragma unroll
    for (int i = 0; i < 4; ++i) {
        const int n = r8 + i * 8;
        out[(size_t)(n0 + n) * K + k0 + c] = f2bf(tile[c][n]);
    }
}

// ---------------- bf16 MFMA GEMM: C[M,N](f32) = A[M,K](bf16) @ Bt[N,K](bf16) ------------------
__global__ __launch_bounds__(256)
void gemm_bf16(const unsigned short* __restrict__ A, const unsigned short* __restrict__ Bt,
               const float* __restrict__ bias, const float* __restrict__ resid,
               float* __restrict__ C, int M, int N, int K)
{
    __shared__ unsigned short As[128 * 64];
    __shared__ unsigned short Bs[128 * 64];
    const int tid = threadIdx.x;
    const int wave = tid >> 6, lane = tid & 63;
    const int bm = blockIdx.x * 128, bn = blockIdx.y * 128;
    const int wr = wave >> 1, wc = wave & 1;
    const int stR = lane >> 3;
    const int stC = (lane & 7) * 8;

    const unsigned short* Abase = A + (size_t)(bm + wave * 32 + stR) * K + stC;
    const unsigned short* Bbase = Bt + (size_t)(bn + wave * 32 + stR) * K + stC;
    unsigned short* AsW = As + wave * 2048;
    unsigned short* BsW = Bs + wave * 2048;

    f32x4 acc[4][4] = {};
    const int fr = lane & 15;
    const int fko = (lane >> 4) * 8;

    for (int k0 = 0; k0 < K; k0 += 64) {
#pragma unroll
        for (int i = 0; i < 4; ++i) {
            gload_lds16(Abase + (size_t)i * 8 * K + k0, AsW + i * 512);
            gload_lds16(Bbase + (size_t)i * 8 * K + k0, BsW + i * 512);
        }
        __syncthreads();
        bf16x8 af[4][2], bfr[4][2];
#pragma unroll
        for (int m = 0; m < 4; ++m) {
            const unsigned short* ap = As + (wr * 64 + m * 16 + fr) * 64 + fko;
            af[m][0] = *(const bf16x8*)(ap);
            af[m][1] = *(const bf16x8*)(ap + 32);
        }
#pragma unroll
        for (int n = 0; n < 4; ++n) {
            const unsigned short* bp = Bs + (wc * 64 + n * 16 + fr) * 64 + fko;
            bfr[n][0] = *(const bf16x8*)(bp);
            bfr[n][1] = *(const bf16x8*)(bp + 32);
        }
#pragma unroll
        for (int m = 0; m < 4; ++m)
#pragma unroll
            for (int n = 0; n < 4; ++n) {
                acc[m][n] = __builtin_amdgcn_mfma_f32_16x16x32_bf16(af[m][0], bfr[n][0], acc[m][n], 0, 0, 0);
                acc[m][n] = __builtin_amdgcn_mfma_f32_16x16x32_bf16(af[m][1], bfr[n][1], acc[m][n], 0, 0, 0);
            }
        __syncthreads();
    }
    const int fq = lane >> 4;
#pragma unroll
    for (int n = 0; n < 4; ++n) {
        const int col = bn + wc * 64 + n * 16 + fr;
        const float bv = bias ? bias[col] : 0.f;
#pragma unroll
        for (int m = 0; m < 4; ++m) {
#pragma unroll
            for (int j = 0; j < 4; ++j) {
                const int row = bm + wr * 64 + m * 16 + fq * 4 + j;
                float v = acc[m][n][j] + bv;
                if (resid) v += resid[(size_t)row * N + col];
                C[(size_t)row * N + col] = v;
            }
        }
    }
}

// ---------------- fused attention per (b, h, 64-row q tile); writes ctx as bf16 ---------------
__global__ __launch_bounds__(256)
void attn_f32(const float* __restrict__ q, const float* __restrict__ k,
              const float* __restrict__ v, unsigned short* __restrict__ ctxb)
{
    __shared__ float S[64][512];
    __shared__ float KV[64][68];
    const int tid = threadIdx.x;
    const int wg = blockIdx.x;
    const int qt = wg & 7, h = (wg >> 3) & 7, b = wg >> 6;
    const int r = tid >> 2, quad = tid & 3;
    const int t0 = qt * 64;

    float4 qreg[16];
    {
        const float* qrow = q + ((size_t)(b * 512 + t0 + r) * 512) + h * 64;
#pragma unroll
        for (int i = 0; i < 16; ++i) {
            float4 t = *(const float4*)(qrow + i * 4);
            t.x *= 0.125f; t.y *= 0.125f; t.z *= 0.125f; t.w *= 0.125f;
            qreg[i] = t;
        }
    }
    for (int st = 0; st < 8; ++st) {
        {
            const int s = tid >> 2, d0 = quad * 16;
            const float* krow = k + ((size_t)(b * 512 + st * 64 + s) * 512) + h * 64 + d0;
#pragma unroll
            for (int j = 0; j < 4; ++j)
                *(float4*)&KV[s][d0 + j * 4] = *(const float4*)(krow + j * 4);
        }
        __syncthreads();
        const int sbase = quad * 16;
#pragma unroll 4
        for (int sp = 0; sp < 16; ++sp) {
            const int s = sbase + sp;
            float accd = 0.f;
#pragma unroll
            for (int kk = 0; kk < 16; ++kk) {
                const float4 kv = *(const float4*)&KV[s][kk * 4];
                accd += qreg[kk].x * kv.x + qreg[kk].y * kv.y +
                        qreg[kk].z * kv.z + qreg[kk].w * kv.w;
            }
            S[r][st * 64 + s] = accd;
        }
        __syncthreads();
    }
    const int c0 = quad * 128;
    float mx = -1e30f;
    for (int c4 = 0; c4 < 32; ++c4) {
        const float4 sv = *(const float4*)&S[r][c0 + c4 * 4];
        mx = fmaxf(mx, fmaxf(fmaxf(sv.x, sv.y), fmaxf(sv.z, sv.w)));
    }
    mx = fmaxf(mx, __shfl_xor(mx, 1));
    mx = fmaxf(mx, __shfl_xor(mx, 2));
    float sum = 0.f;
    for (int c4 = 0; c4 < 32; ++c4) {
        float4 sv = *(const float4*)&S[r][c0 + c4 * 4];
        sv.x = __expf(sv.x - mx); sv.y = __expf(sv.y - mx);
        sv.z = __expf(sv.z - mx); sv.w = __expf(sv.w - mx);
        sum += sv.x + sv.y + sv.z + sv.w;
        *(float4*)&S[r][c0 + c4 * 4] = sv;
    }
    sum += __shfl_xor(sum, 1);
    sum += __shfl_xor(sum, 2);
    const float inv = 1.0f / sum;
    __syncthreads();
    float o[16] = {};
    const int d0 = quad * 16;
    for (int st = 0; st < 8; ++st) {
        {
            const int s = tid >> 2;
            const float* vrow = v + ((size_t)(b * 512 + st * 64 + s) * 512) + h * 64 + d0;
#pragma unroll
            for (int j = 0; j < 4; ++j)
                *(float4*)&KV[s][d0 + j * 4] = *(const float4*)(vrow + j * 4);
        }
        __syncthreads();
        for (int s4 = 0; s4 < 16; ++s4) {
            const float4 p = *(const float4*)&S[r][st * 64 + s4 * 4];
            const float pv[4] = {p.x, p.y, p.z, p.w};
#pragma unroll
            for (int jj = 0; jj < 4; ++jj) {
                const int s = s4 * 4 + jj;
#pragma unroll
                for (int i = 0; i < 4; ++i) {
                    const float4 vv = *(const float4*)&KV[s][d0 + i * 4];
                    o[i * 4 + 0] = fmaf(pv[jj], vv.x, o[i * 4 + 0]);
                    o[i * 4 + 1] = fmaf(pv[jj], vv.y, o[i * 4 + 1]);
                    o[i * 4 + 2] = fmaf(pv[jj], vv.z, o[i * 4 + 2]);
                    o[i * 4 + 3] = fmaf(pv[jj], vv.w, o[i * 4 + 3]);
                }
            }
        }
        __syncthreads();
    }
    unsigned short* crow = ctxb + ((size_t)(b * 512 + t0 + r) * 512) + h * 64 + d0;
#pragma unroll
    for (int i = 0; i < 4; ++i) {
        const us4 t = {f2bf(o[i * 4 + 0] * inv), f2bf(o[i * 4 + 1] * inv),
                       f2bf(o[i * 4 + 2] * inv), f2bf(o[i * 4 + 3] * inv)};
        *(us4*)(crow + i * 4) = t;
    }
}

// ---------------- layernorm (rows of 512), optional bf16 side output --------------------------
__global__ __launch_bounds__(256)
void ln_f32(const float* __restrict__ in, float* __restrict__ out,
            const float* __restrict__ g, const float* __restrict__ bb,
            unsigned short* __restrict__ outb)
{
    const int lane = threadIdx.x & 63;
    const int row = blockIdx.x * 4 + (threadIdx.x >> 6);
    const float* x = in + (size_t)row * 512;
    const float4 a = *(const float4*)(x + lane * 4);
    const float4 c = *(const float4*)(x + 256 + lane * 4);
    float s = a.x + a.y + a.z + a.w + c.x + c.y + c.z + c.w;
#pragma unroll
    for (int off = 1; off < 64; off <<= 1) s += __shfl_xor(s, off);
    const float mu = s * (1.0f / 512.0f);
    float vs = 0.f;
    vs += (a.x - mu) * (a.x - mu) + (a.y - mu) * (a.y - mu);
    vs += (a.z - mu) * (a.z - mu) + (a.w - mu) * (a.w - mu);
    vs += (c.x - mu) * (c.x - mu) + (c.y - mu) * (c.y - mu);
    vs += (c.z - mu) * (c.z - mu) + (c.w - mu) * (c.w - mu);
#pragma unroll
    for (int off = 1; off < 64; off <<= 1) vs += __shfl_xor(vs, off);
    const float rstd = rsqrtf(vs * (1.0f / 512.0f) + 1e-3f);
    const float4 g1 = *(const float4*)(g + lane * 4);
    const float4 g2 = *(const float4*)(g + 256 + lane * 4);
    const float4 b1 = *(const float4*)(bb + lane * 4);
    const float4 b2 = *(const float4*)(bb + 256 + lane * 4);
    float* y = out + (size_t)row * 512;
    const float4 o1 = {(a.x - mu) * rstd * g1.x + b1.x, (a.y - mu) * rstd * g1.y + b1.y,
                       (a.z - mu) * rstd * g1.z + b1.z, (a.w - mu) * rstd * g1.w + b1.w};
    const float4 o2 = {(c.x - mu) * rstd * g2.x + b2.x, (c.y - mu) * rstd * g2.y + b2.y,
                       (c.z - mu) * rstd * g2.z + b2.z, (c.w - mu) * rstd * g2.w + b2.w};
    *(float4*)(y + lane * 4) = o1;
    *(float4*)(y + 256 + lane * 4) = o2;
    if (outb) {
        unsigned short* yb = outb + (size_t)row * 512;
        const us4 p1 = {f2bf(o1.x), f2bf(o1.y), f2bf(o1.z), f2bf(o1.w)};
        const us4 p2 = {f2bf(o2.x), f2bf(o2.y), f2bf(o2.z), f2bf(o2.w)};
        *(us4*)(yb + lane * 4) = p1;
        *(us4*)(yb + 256 + lane * 4) = p2;
    }
}

// ---------------- persistent GRU, XCD-pinned: 8 WGs on ONE XCD, L2-coherent sync --------------
// Launch 128 WGs; after a one-time quiescence barrier each WG knows the per-XCD WG counts and
// deterministically elects the 8 lowest-ranked WGs on the most-populated XCD. All hot-loop sync
// is L2-local: plain stores (write-through L1) + unflagged global_atomic_add (L2 RMW) + sc0
// loads (L1 bypass). No wbl2/inv cache maintenance per step.
__global__ __launch_bounds__(256, 1)
void gru_persist(const float* __restrict__ rk,      // gru_rk [512][1536] fp32
                 const float* __restrict__ xp,      // [8192][1536] fp32 (bias0 included)
                 const float* __restrict__ rb,      // recurrent bias [1536]
                 unsigned short* __restrict__ hbuf, // [2][16*512] bf16 (zeroed)
                 unsigned short* __restrict__ goutb,// [8192][512] bf16
                 unsigned int* __restrict__ bar,    // step barrier counter (zeroed)
                 unsigned int* __restrict__ ctl)    // [16]: 0..7 per-XCD rank, 8 started (zeroed)
{
    __shared__ int sh_part, sh_memb;
    const int tid = threadIdx.x;

    if (tid == 0) {
        unsigned int xcc;
        asm("s_getreg_b32 %0, hwreg(HW_REG_XCC_ID)" : "=s"(xcc));
        xcc &= 7u;
        const unsigned int rank =
            __hip_atomic_fetch_add(&ctl[xcc], 1u, __ATOMIC_RELAXED, __HIP_MEMORY_SCOPE_AGENT);
        __hip_atomic_fetch_add(&ctl[8], 1u, __ATOMIC_ACQ_REL, __HIP_MEMORY_SCOPE_AGENT);
        unsigned int spins = 0;
        while (__hip_atomic_load(&ctl[8], __ATOMIC_ACQUIRE, __HIP_MEMORY_SCOPE_AGENT)
               < (unsigned)GRID_WGS) {
            __builtin_amdgcn_s_sleep(1);
            if (++spins > (1u << 20)) break;
        }
        unsigned int cnt[8];
#pragma unroll
        for (int i = 0; i < 8; ++i)
            cnt[i] = __hip_atomic_load(&ctl[i], __ATOMIC_ACQUIRE, __HIP_MEMORY_SCOPE_AGENT);
        int best = 0;
#pragma unroll
        for (int i = 1; i < 8; ++i)
            if (cnt[i] > cnt[best]) best = i;
        sh_part = (xcc == (unsigned)best && rank < 8u) ? 1 : 0;
        sh_memb = (int)rank;
    }
    __syncthreads();
    if (!sh_part) return;
    const int member = sh_memb;          // 0..7

    const int wv = tid >> 6, l = tid & 63;
    const int wgi = member * 4 + wv;     // global wave index 0..31
    const int lo16 = l & 15;
    const int hi4 = l >> 4;              // 0..3
    const int gc = wgi * 16 + lo16;      // this lane's output h-col

    // ---- preload B fragments: B[g][kt], lane slot j <-> k = kt*32 + hi4*8 + j
    bf16x8 B[3][16];
#pragma unroll
    for (int g = 0; g < 3; ++g)
#pragma unroll
        for (int kt = 0; kt < 16; ++kt) {
            bf16x8 bv;
#pragma unroll
            for (int j = 0; j < 8; ++j) {
                const int k = kt * 32 + hi4 * 8 + j;
                bv[j] = (short)f2bf(rk[(size_t)k * 1536 + g * 512 + gc]);
            }
            B[g][kt] = bv;
        }
    const float rbz = rb[gc], rbr = rb[512 + gc], rbh = rb[1024 + gc];
    float hst[4] = {0.f, 0.f, 0.f, 0.f};

    // prefetch xp for t=0
    float xzv[4], xrv[4], xhv[4];
#pragma unroll
    for (int j = 0; j < 4; ++j) {
        const float* xrow = xp + ((size_t)((hi4 * 4 + j) * 512)) * 1536 + gc;
        xzv[j] = xrow[0]; xrv[j] = xrow[512]; xhv[j] = xrow[1024];
    }

    for (int t = 0; t < 512; ++t) {
        const unsigned short* hr = hbuf + (size_t)(t & 1) * (16 * 512);
        unsigned short* hw = hbuf + (size_t)((t + 1) & 1) * (16 * 512);
        // A frags via sc0 loads (L1 bypass -> read XCD L2 where peers' stores live)
        bf16x8 A[16];
#pragma unroll
        for (int kt = 0; kt < 16; ++kt) {
            const unsigned short* ap = hr + lo16 * 512 + kt * 32 + hi4 * 8;
            asm volatile("global_load_dwordx4 %0, %1, off sc0"
                         : "=v"(A[kt]) : "v"(ap) : "memory");
        }
        asm volatile("s_waitcnt vmcnt(0)" ::: "memory");
        __builtin_amdgcn_sched_barrier(0);

        f32x4 accz = {0.f, 0.f, 0.f, 0.f};
        f32x4 accr = {0.f, 0.f, 0.f, 0.f};
        f32x4 acch = {0.f, 0.f, 0.f, 0.f};
#pragma unroll
        for (int kt = 0; kt < 16; ++kt) {
            accz = __builtin_amdgcn_mfma_f32_16x16x32_bf16(A[kt], B[0][kt], accz, 0, 0, 0);
            accr = __builtin_amdgcn_mfma_f32_16x16x32_bf16(A[kt], B[1][kt], accr, 0, 0, 0);
            acch = __builtin_amdgcn_mfma_f32_16x16x32_bf16(A[kt], B[2][kt], acch, 0, 0, 0);
        }
        // gates + state update; D layout: row b = hi4*4 + j, col = lo16
        float hn[4];
#pragma unroll
        for (int j = 0; j < 4; ++j) {
            const int b = hi4 * 4 + j;
            const float z = sigmoidf_(xzv[j] + accz[j] + rbz);
            const float r = sigmoidf_(xrv[j] + accr[j] + rbr);
            const float hh = fmaxf(xhv[j] + r * (acch[j] + rbh), 0.f);
            const float hnew = z * hst[j] + (1.f - z) * hh;
            hst[j] = hnew; hn[j] = hnew;
            hw[b * 512 + gc] = f2bf(hnew);   // plain store -> write-through to local L2
        }
        __syncthreads();   // drains vmcnt for every wave -> all WG h-stores in L2
        if (tid == 0)
            asm volatile("global_atomic_add %0, %1, off"
                         :: "v"(bar), "v"(1u) : "memory");   // L2-local RMW (no sc flags)
        // deferred off critical path: gout stores for step t
#pragma unroll
        for (int j = 0; j < 4; ++j)
            goutb[((size_t)((hi4 * 4 + j) * 512 + t)) * 512 + gc] = f2bf(hn[j]);
        if (t < 511) {
            // prefetch xp for t+1 (completes during spin)
#pragma unroll
            for (int j = 0; j < 4; ++j) {
                const float* xrow = xp + ((size_t)((hi4 * 4 + j) * 512 + t + 1)) * 1536 + gc;
                xzv[j] = xrow[0]; xrv[j] = xrow[512]; xhv[j] = xrow[1024];
            }
            if (tid < 64) {
                const unsigned int target = 8u * (unsigned int)(t + 1);
                unsigned int cur, spins = 0;
                do {
                    asm volatile("global_load_dword %0, %1, off sc0\n\ts_waitcnt vmcnt(0)"
                                 : "=v"(cur) : "v"(bar) : "memory");
                } while (cur < target && ++spins < (1u << 17));
            }
            __syncthreads();
        }
    }
}

extern "C" void kernel_launch(void* const* d_in, const int* in_sizes, int n_in,
                              void* d_out, int out_size, void* d_ws, size_t ws_size,
                              hipStream_t stream)
{
    const float* x     = (const float*)d_in[0];
    const float* Wq    = (const float*)d_in[1];
    const float* bq    = (const float*)d_in[2];
    const float* Wk    = (const float*)d_in[3];
    const float* bk    = (const float*)d_in[4];
    const float* Wv    = (const float*)d_in[5];
    const float* bv    = (const float*)d_in[6];
    const float* Wo    = (const float*)d_in[7];
    const float* bo    = (const float*)d_in[8];
    const float* ln1g  = (const float*)d_in[9];
    const float* ln1b  = (const float*)d_in[10];
    const float* gruk  = (const float*)d_in[11];
    const float* grurk = (const float*)d_in[12];
    const float* grub  = (const float*)d_in[13];
    const float* Wd    = (const float*)d_in[14];
    const float* bd    = (const float*)d_in[15];
    const float* ln2g  = (const float*)d_in[16];
    const float* ln2b  = (const float*)d_in[17];
    float* out = (float*)d_out;

    char* base = (char*)d_ws;
    const size_t MB = 1024 * 1024;
    float*          Q0   = (float*)base;                      // 48 MB: q/k/v -> xp -> dense-out
    float*          R4   = (float*)(base + 48 * MB);          // 16 MB: x1
    unsigned short* S1   = (unsigned short*)(base + 64 * MB); // 8 MB: xb -> ctxb -> x1b -> goutb
    unsigned short* WT   = (unsigned short*)(base + 72 * MB); // 4 MB weights
    unsigned short* wqT  = WT;
    unsigned short* wkT  = WT + 256 * 1024;
    unsigned short* wvT  = WT + 512 * 1024;
    unsigned short* woT  = WT + 768 * 1024;
    unsigned short* gkT  = WT + 1024 * 1024;    // 1536x512
    unsigned short* wdT  = WT + 1792 * 1024;
    unsigned short* hbuf = (unsigned short*)(base + 76 * MB); // 2*16*512 bf16 = 32 KB
    unsigned int*   bar  = (unsigned int*)(base + 76 * MB + 64 * 1024);
    unsigned int*   ctl  = (unsigned int*)(base + 76 * MB + 64 * 1024 + 128);

    float* q = Q0;
    float* k = Q0 + (size_t)4 * MB;
    float* v = Q0 + (size_t)8 * MB;
    float* xpbuf = Q0;
    float* dout  = Q0;

    const dim3 blk(256);
    const dim3 g512(8192 / 128, 512 / 128);
    const dim3 g1536(8192 / 128, 1536 / 128);

    f2bf_kernel<<<dim3(4096), blk, 0, stream>>>(x, S1);
    transpose_bf16<<<dim3(16, 16), blk, 0, stream>>>(Wq, wqT, 512, 512);
    transpose_bf16<<<dim3(16, 16), blk, 0, stream>>>(Wk, wkT, 512, 512);
    transpose_bf16<<<dim3(16, 16), blk, 0, stream>>>(Wv, wvT, 512, 512);
    transpose_bf16<<<dim3(16, 16), blk, 0, stream>>>(Wo, woT, 512, 512);
    transpose_bf16<<<dim3(48, 16), blk, 0, stream>>>(gruk, gkT, 512, 1536);
    transpose_bf16<<<dim3(16, 16), blk, 0, stream>>>(Wd, wdT, 512, 512);
    gemm_bf16<<<g512, blk, 0, stream>>>(S1, wqT, bq, nullptr, q, 8192, 512, 512);
    gemm_bf16<<<g512, blk, 0, stream>>>(S1, wkT, bk, nullptr, k, 8192, 512, 512);
    gemm_bf16<<<g512, blk, 0, stream>>>(S1, wvT, bv, nullptr, v, 8192, 512, 512);
    attn_f32<<<dim3(1024), blk, 0, stream>>>(q, k, v, S1);
    gemm_bf16<<<g512, blk, 0, stream>>>(S1, woT, bo, x, R4, 8192, 512, 512);
    ln_f32<<<dim3(2048), blk, 0, stream>>>(R4, R4, ln1g, ln1b, S1);
    gemm_bf16<<<g1536, blk, 0, stream>>>(S1, gkT, grub, nullptr, xpbuf, 8192, 1536, 512);
    // persistent GRU (XCD-pinned)
    hipMemsetAsync(hbuf, 0, 2 * 16 * 512 * sizeof(unsigned short), stream);
    hipMemsetAsync(bar, 0, 512, stream);   // covers bar + ctl
    gru_persist<<<dim3(GRID_WGS), blk, 0, stream>>>(grurk, xpbuf, grub + 1536, hbuf, S1, bar, ctl);
    gemm_bf16<<<g512, blk, 0, stream>>>(S1, wdT, bd, R4, dout, 8192, 512, 512);
    ln_f32<<<dim3(2048), blk, 0, stream>>>(dout, out, ln2g, ln2b, nullptr);
}

// Round 5
// 2336.283 us; speedup vs baseline: 1276.1983x; 1276.1983x over previous
//
#include <hip/hip_runtime.h>
#include <math.h>

// B=16, T=512, F=512, H=8, D=64; rows = B*T = 8192
#define GRID_WGS 128   // launched WGs for GRU; 8 elected (same XCD) participate

typedef __attribute__((ext_vector_type(8))) short bf16x8;
typedef __attribute__((ext_vector_type(4))) float f32x4;
typedef __attribute__((ext_vector_type(4))) unsigned short us4;

static __device__ __forceinline__ float sigmoidf_(float x) {
    return 1.0f / (1.0f + __expf(-x));
}
static __device__ __forceinline__ unsigned short f2bf(float f) {
    unsigned int u = __float_as_uint(f);
    u += 0x7fffu + ((u >> 16) & 1u);
    return (unsigned short)(u >> 16);
}
static __device__ __forceinline__ void gload_lds16(const void* g, void* l) {
    __builtin_amdgcn_global_load_lds(
        (const __attribute__((address_space(1))) unsigned int*)g,
        (__attribute__((address_space(3))) unsigned int*)l, 16, 0, 0);
}

// ---------------- fp32 -> bf16 convert --------------------------------------------------------
__global__ __launch_bounds__(256)
void f2bf_kernel(const float* __restrict__ in, unsigned short* __restrict__ out)
{
    const int i = (blockIdx.x * 256 + threadIdx.x) * 4;
    const float4 v = *(const float4*)(in + i);
    const us4 o = {f2bf(v.x), f2bf(v.y), f2bf(v.z), f2bf(v.w)};
    *(us4*)(out + i) = o;
}

// ---------------- transpose+convert: in [K][N] f32 -> out [N][K] bf16 -------------------------
__global__ __launch_bounds__(256)
void transpose_bf16(const float* __restrict__ in, unsigned short* __restrict__ out,
                    int K, int N)
{
    __shared__ float tile[32][33];
    const int n0 = blockIdx.x * 32, k0 = blockIdx.y * 32;
    const int c = threadIdx.x & 31, r8 = threadIdx.x >> 5;
#pragma unroll
    for (int i = 0; i < 4; ++i) {
        const int k = r8 + i * 8;
        tile[k][c] = in[(size_t)(k0 + k) * N + n0 + c];
    }
    __syncthreads();
#pragma unroll
    for (int i = 0; i < 4; ++i) {
        const int n = r8 + i * 8;
        out[(size_t)(n0 + n) * K + k0 + c] = f2bf(tile[c][n]);
    }
}

// ---------------- bf16 MFMA GEMM: C[M,N](f32) = A[M,K](bf16) @ Bt[N,K](bf16) ------------------
__global__ __launch_bounds__(256)
void gemm_bf16(const unsigned short* __restrict__ A, const unsigned short* __restrict__ Bt,
               const float* __restrict__ bias, const float* __restrict__ resid,
               float* __restrict__ C, int M, int N, int K)
{
    __shared__ unsigned short As[128 * 64];
    __shared__ unsigned short Bs[128 * 64];
    const int tid = threadIdx.x;
    const int wave = tid >> 6, lane = tid & 63;
    const int bm = blockIdx.x * 128, bn = blockIdx.y * 128;
    const int wr = wave >> 1, wc = wave & 1;
    const int stR = lane >> 3;
    const int stC = (lane & 7) * 8;

    const unsigned short* Abase = A + (size_t)(bm + wave * 32 + stR) * K + stC;
    const unsigned short* Bbase = Bt + (size_t)(bn + wave * 32 + stR) * K + stC;
    unsigned short* AsW = As + wave * 2048;
    unsigned short* BsW = Bs + wave * 2048;

    f32x4 acc[4][4] = {};
    const int fr = lane & 15;
    const int fko = (lane >> 4) * 8;

    for (int k0 = 0; k0 < K; k0 += 64) {
#pragma unroll
        for (int i = 0; i < 4; ++i) {
            gload_lds16(Abase + (size_t)i * 8 * K + k0, AsW + i * 512);
            gload_lds16(Bbase + (size_t)i * 8 * K + k0, BsW + i * 512);
        }
        __syncthreads();
        bf16x8 af[4][2], bfr[4][2];
#pragma unroll
        for (int m = 0; m < 4; ++m) {
            const unsigned short* ap = As + (wr * 64 + m * 16 + fr) * 64 + fko;
            af[m][0] = *(const bf16x8*)(ap);
            af[m][1] = *(const bf16x8*)(ap + 32);
        }
#pragma unroll
        for (int n = 0; n < 4; ++n) {
            const unsigned short* bp = Bs + (wc * 64 + n * 16 + fr) * 64 + fko;
            bfr[n][0] = *(const bf16x8*)(bp);
            bfr[n][1] = *(const bf16x8*)(bp + 32);
        }
#pragma unroll
        for (int m = 0; m < 4; ++m)
#pragma unroll
            for (int n = 0; n < 4; ++n) {
                acc[m][n] = __builtin_amdgcn_mfma_f32_16x16x32_bf16(af[m][0], bfr[n][0], acc[m][n], 0, 0, 0);
                acc[m][n] = __builtin_amdgcn_mfma_f32_16x16x32_bf16(af[m][1], bfr[n][1], acc[m][n], 0, 0, 0);
            }
        __syncthreads();
    }
    const int fq = lane >> 4;
#pragma unroll
    for (int n = 0; n < 4; ++n) {
        const int col = bn + wc * 64 + n * 16 + fr;
        const float bv = bias ? bias[col] : 0.f;
#pragma unroll
        for (int m = 0; m < 4; ++m) {
#pragma unroll
            for (int j = 0; j < 4; ++j) {
                const int row = bm + wr * 64 + m * 16 + fq * 4 + j;
                float v = acc[m][n][j] + bv;
                if (resid) v += resid[(size_t)row * N + col];
                C[(size_t)row * N + col] = v;
            }
        }
    }
}

// ---------------- fused attention per (b, h, 64-row q tile); writes ctx as bf16 ---------------
__global__ __launch_bounds__(256)
void attn_f32(const float* __restrict__ q, const float* __restrict__ k,
              const float* __restrict__ v, unsigned short* __restrict__ ctxb)
{
    __shared__ float S[64][512];
    __shared__ float KV[64][68];
    const int tid = threadIdx.x;
    const int wg = blockIdx.x;
    const int qt = wg & 7, h = (wg >> 3) & 7, b = wg >> 6;
    const int r = tid >> 2, quad = tid & 3;
    const int t0 = qt * 64;

    float4 qreg[16];
    {
        const float* qrow = q + ((size_t)(b * 512 + t0 + r) * 512) + h * 64;
#pragma unroll
        for (int i = 0; i < 16; ++i) {
            float4 t = *(const float4*)(qrow + i * 4);
            t.x *= 0.125f; t.y *= 0.125f; t.z *= 0.125f; t.w *= 0.125f;
            qreg[i] = t;
        }
    }
    for (int st = 0; st < 8; ++st) {
        {
            const int s = tid >> 2, d0 = quad * 16;
            const float* krow = k + ((size_t)(b * 512 + st * 64 + s) * 512) + h * 64 + d0;
#pragma unroll
            for (int j = 0; j < 4; ++j)
                *(float4*)&KV[s][d0 + j * 4] = *(const float4*)(krow + j * 4);
        }
        __syncthreads();
        const int sbase = quad * 16;
#pragma unroll 4
        for (int sp = 0; sp < 16; ++sp) {
            const int s = sbase + sp;
            float accd = 0.f;
#pragma unroll
            for (int kk = 0; kk < 16; ++kk) {
                const float4 kv = *(const float4*)&KV[s][kk * 4];
                accd += qreg[kk].x * kv.x + qreg[kk].y * kv.y +
                        qreg[kk].z * kv.z + qreg[kk].w * kv.w;
            }
            S[r][st * 64 + s] = accd;
        }
        __syncthreads();
    }
    const int c0 = quad * 128;
    float mx = -1e30f;
    for (int c4 = 0; c4 < 32; ++c4) {
        const float4 sv = *(const float4*)&S[r][c0 + c4 * 4];
        mx = fmaxf(mx, fmaxf(fmaxf(sv.x, sv.y), fmaxf(sv.z, sv.w)));
    }
    mx = fmaxf(mx, __shfl_xor(mx, 1));
    mx = fmaxf(mx, __shfl_xor(mx, 2));
    float sum = 0.f;
    for (int c4 = 0; c4 < 32; ++c4) {
        float4 sv = *(const float4*)&S[r][c0 + c4 * 4];
        sv.x = __expf(sv.x - mx); sv.y = __expf(sv.y - mx);
        sv.z = __expf(sv.z - mx); sv.w = __expf(sv.w - mx);
        sum += sv.x + sv.y + sv.z + sv.w;
        *(float4*)&S[r][c0 + c4 * 4] = sv;
    }
    sum += __shfl_xor(sum, 1);
    sum += __shfl_xor(sum, 2);
    const float inv = 1.0f / sum;
    __syncthreads();
    float o[16] = {};
    const int d0 = quad * 16;
    for (int st = 0; st < 8; ++st) {
        {
            const int s = tid >> 2;
            const float* vrow = v + ((size_t)(b * 512 + st * 64 + s) * 512) + h * 64 + d0;
#pragma unroll
            for (int j = 0; j < 4; ++j)
                *(float4*)&KV[s][d0 + j * 4] = *(const float4*)(vrow + j * 4);
        }
        __syncthreads();
        for (int s4 = 0; s4 < 16; ++s4) {
            const float4 p = *(const float4*)&S[r][st * 64 + s4 * 4];
            const float pv[4] = {p.x, p.y, p.z, p.w};
#pragma unroll
            for (int jj = 0; jj < 4; ++jj) {
                const int s = s4 * 4 + jj;
#pragma unroll
                for (int i = 0; i < 4; ++i) {
                    const float4 vv = *(const float4*)&KV[s][d0 + i * 4];
                    o[i * 4 + 0] = fmaf(pv[jj], vv.x, o[i * 4 + 0]);
                    o[i * 4 + 1] = fmaf(pv[jj], vv.y, o[i * 4 + 1]);
                    o[i * 4 + 2] = fmaf(pv[jj], vv.z, o[i * 4 + 2]);
                    o[i * 4 + 3] = fmaf(pv[jj], vv.w, o[i * 4 + 3]);
                }
            }
        }
        __syncthreads();
    }
    unsigned short* crow = ctxb + ((size_t)(b * 512 + t0 + r) * 512) + h * 64 + d0;
#pragma unroll
    for (int i = 0; i < 4; ++i) {
        const us4 t = {f2bf(o[i * 4 + 0] * inv), f2bf(o[i * 4 + 1] * inv),
                       f2bf(o[i * 4 + 2] * inv), f2bf(o[i * 4 + 3] * inv)};
        *(us4*)(crow + i * 4) = t;
    }
}

// ---------------- layernorm (rows of 512), optional bf16 side output --------------------------
__global__ __launch_bounds__(256)
void ln_f32(const float* __restrict__ in, float* __restrict__ out,
            const float* __restrict__ g, const float* __restrict__ bb,
            unsigned short* __restrict__ outb)
{
    const int lane = threadIdx.x & 63;
    const int row = blockIdx.x * 4 + (threadIdx.x >> 6);
    const float* x = in + (size_t)row * 512;
    const float4 a = *(const float4*)(x + lane * 4);
    const float4 c = *(const float4*)(x + 256 + lane * 4);
    float s = a.x + a.y + a.z + a.w + c.x + c.y + c.z + c.w;
#pragma unroll
    for (int off = 1; off < 64; off <<= 1) s += __shfl_xor(s, off);
    const float mu = s * (1.0f / 512.0f);
    float vs = 0.f;
    vs += (a.x - mu) * (a.x - mu) + (a.y - mu) * (a.y - mu);
    vs += (a.z - mu) * (a.z - mu) + (a.w - mu) * (a.w - mu);
    vs += (c.x - mu) * (c.x - mu) + (c.y - mu) * (c.y - mu);
    vs += (c.z - mu) * (c.z - mu) + (c.w - mu) * (c.w - mu);
#pragma unroll
    for (int off = 1; off < 64; off <<= 1) vs += __shfl_xor(vs, off);
    const float rstd = rsqrtf(vs * (1.0f / 512.0f) + 1e-3f);
    const float4 g1 = *(const float4*)(g + lane * 4);
    const float4 g2 = *(const float4*)(g + 256 + lane * 4);
    const float4 b1 = *(const float4*)(bb + lane * 4);
    const float4 b2 = *(const float4*)(bb + 256 + lane * 4);
    float* y = out + (size_t)row * 512;
    const float4 o1 = {(a.x - mu) * rstd * g1.x + b1.x, (a.y - mu) * rstd * g1.y + b1.y,
                       (a.z - mu) * rstd * g1.z + b1.z, (a.w - mu) * rstd * g1.w + b1.w};
    const float4 o2 = {(c.x - mu) * rstd * g2.x + b2.x, (c.y - mu) * rstd * g2.y + b2.y,
                       (c.z - mu) * rstd * g2.z + b2.z, (c.w - mu) * rstd * g2.w + b2.w};
    *(float4*)(y + lane * 4) = o1;
    *(float4*)(y + 256 + lane * 4) = o2;
    if (outb) {
        unsigned short* yb = outb + (size_t)row * 512;
        const us4 p1 = {f2bf(o1.x), f2bf(o1.y), f2bf(o1.z), f2bf(o1.w)};
        const us4 p2 = {f2bf(o2.x), f2bf(o2.y), f2bf(o2.z), f2bf(o2.w)};
        *(us4*)(yb + lane * 4) = p1;
        *(us4*)(yb + 256 + lane * 4) = p2;
    }
}

// ---------------- persistent GRU, XCD-pinned: 8 WGs on ONE XCD -------------------------------
// Election (proven r4): 128 WGs launched; per-XCD counts via device atomics; the 8 lowest-rank
// WGs on the most-populated XCD participate, rest exit.
// Hot loop (fixed r5): h via plain stores -> shared XCD L2, read back with sc0 (L1-bypass).
// Barrier counter lives at the DEVICE atomic point (L3): arrivals = unflagged global_atomic_add;
// poll = single-lane atomic-add-0 with sc0 (return-old) -- executes at the same L3 point, so it
// can never read a stale L2 copy (r4's bug). No wbl2/inv anywhere in the loop.
__global__ __launch_bounds__(256, 1)
void gru_persist(const float* __restrict__ rk,      // gru_rk [512][1536] fp32
                 const float* __restrict__ xp,      // [8192][1536] fp32 (bias0 included)
                 const float* __restrict__ rb,      // recurrent bias [1536]
                 unsigned short* __restrict__ hbuf, // [2][16*512] bf16 (zeroed)
                 unsigned short* __restrict__ goutb,// [8192][512] bf16
                 unsigned int* __restrict__ bar,    // step barrier counter (zeroed)
                 unsigned int* __restrict__ ctl)    // [16]: 0..7 per-XCD rank, 8 started (zeroed)
{
    __shared__ int sh_part, sh_memb;
    const int tid = threadIdx.x;

    if (tid == 0) {
        unsigned int xcc;
        asm("s_getreg_b32 %0, hwreg(HW_REG_XCC_ID)" : "=s"(xcc));
        xcc &= 7u;
        const unsigned int rank =
            __hip_atomic_fetch_add(&ctl[xcc], 1u, __ATOMIC_RELAXED, __HIP_MEMORY_SCOPE_AGENT);
        __hip_atomic_fetch_add(&ctl[8], 1u, __ATOMIC_ACQ_REL, __HIP_MEMORY_SCOPE_AGENT);
        unsigned int spins = 0;
        while (__hip_atomic_load(&ctl[8], __ATOMIC_ACQUIRE, __HIP_MEMORY_SCOPE_AGENT)
               < (unsigned)GRID_WGS) {
            __builtin_amdgcn_s_sleep(1);
            if (++spins > (1u << 20)) break;
        }
        unsigned int cnt[8];
#pragma unroll
        for (int i = 0; i < 8; ++i)
            cnt[i] = __hip_atomic_load(&ctl[i], __ATOMIC_ACQUIRE, __HIP_MEMORY_SCOPE_AGENT);
        int best = 0;
#pragma unroll
        for (int i = 1; i < 8; ++i)
            if (cnt[i] > cnt[best]) best = i;
        sh_part = (xcc == (unsigned)best && rank < 8u) ? 1 : 0;
        sh_memb = (int)rank;
    }
    __syncthreads();
    if (!sh_part) return;
    const int member = sh_memb;          // 0..7

    const int wv = tid >> 6, l = tid & 63;
    const int wgi = member * 4 + wv;     // global wave index 0..31
    const int lo16 = l & 15;
    const int hi4 = l >> 4;              // 0..3
    const int gc = wgi * 16 + lo16;      // this lane's output h-col

    // ---- preload B fragments: B[g][kt], lane slot j <-> k = kt*32 + hi4*8 + j
    bf16x8 B[3][16];
#pragma unroll
    for (int g = 0; g < 3; ++g)
#pragma unroll
        for (int kt = 0; kt < 16; ++kt) {
            bf16x8 bv;
#pragma unroll
            for (int j = 0; j < 8; ++j) {
                const int k = kt * 32 + hi4 * 8 + j;
                bv[j] = (short)f2bf(rk[(size_t)k * 1536 + g * 512 + gc]);
            }
            B[g][kt] = bv;
        }
    const float rbz = rb[gc], rbr = rb[512 + gc], rbh = rb[1024 + gc];
    float hst[4] = {0.f, 0.f, 0.f, 0.f};

    // prefetch xp for t=0
    float xzv[4], xrv[4], xhv[4];
#pragma unroll
    for (int j = 0; j < 4; ++j) {
        const float* xrow = xp + ((size_t)((hi4 * 4 + j) * 512)) * 1536 + gc;
        xzv[j] = xrow[0]; xrv[j] = xrow[512]; xhv[j] = xrow[1024];
    }

    for (int t = 0; t < 512; ++t) {
        const unsigned short* hr = hbuf + (size_t)(t & 1) * (16 * 512);
        unsigned short* hw = hbuf + (size_t)((t + 1) & 1) * (16 * 512);
        // A frags via sc0 loads (L1 bypass -> shared XCD L2 holds peers' stores)
        bf16x8 A[16];
#pragma unroll
        for (int kt = 0; kt < 16; ++kt) {
            const unsigned short* ap = hr + lo16 * 512 + kt * 32 + hi4 * 8;
            asm volatile("global_load_dwordx4 %0, %1, off sc0"
                         : "=v"(A[kt]) : "v"(ap) : "memory");
        }
        asm volatile("s_waitcnt vmcnt(0)" ::: "memory");
        __builtin_amdgcn_sched_barrier(0);

        f32x4 accz = {0.f, 0.f, 0.f, 0.f};
        f32x4 accr = {0.f, 0.f, 0.f, 0.f};
        f32x4 acch = {0.f, 0.f, 0.f, 0.f};
#pragma unroll
        for (int kt = 0; kt < 16; ++kt) {
            accz = __builtin_amdgcn_mfma_f32_16x16x32_bf16(A[kt], B[0][kt], accz, 0, 0, 0);
            accr = __builtin_amdgcn_mfma_f32_16x16x32_bf16(A[kt], B[1][kt], accr, 0, 0, 0);
            acch = __builtin_amdgcn_mfma_f32_16x16x32_bf16(A[kt], B[2][kt], acch, 0, 0, 0);
        }
        // gates + state update; D layout: row b = hi4*4 + j, col = lo16
        float hn[4];
#pragma unroll
        for (int j = 0; j < 4; ++j) {
            const int b = hi4 * 4 + j;
            const float z = sigmoidf_(xzv[j] + accz[j] + rbz);
            const float r = sigmoidf_(xrv[j] + accr[j] + rbr);
            const float hh = fmaxf(xhv[j] + r * (acch[j] + rbh), 0.f);
            const float hnew = z * hst[j] + (1.f - z) * hh;
            hst[j] = hnew; hn[j] = hnew;
            hw[b * 512 + gc] = f2bf(hnew);   // plain store: write-through L1 -> shared XCD L2
        }
        __syncthreads();   // all waves' h-stores drained (vmcnt) before arrival
        if (tid == 0)
            asm volatile("global_atomic_add %0, %1, off"
                         :: "v"(bar), "v"(1u) : "memory");   // device atomic point (L3)
        // deferred off critical path: gout stores for step t
#pragma unroll
        for (int j = 0; j < 4; ++j)
            goutb[((size_t)((hi4 * 4 + j) * 512 + t)) * 512 + gc] = f2bf(hn[j]);
        if (t < 511) {
            // prefetch xp for t+1 (completes during spin)
#pragma unroll
            for (int j = 0; j < 4; ++j) {
                const float* xrow = xp + ((size_t)((hi4 * 4 + j) * 512 + t + 1)) * 1536 + gc;
                xzv[j] = xrow[0]; xrv[j] = xrow[512]; xhv[j] = xrow[1024];
            }
            if (tid == 0) {
                // poll at the SAME L3 atomic point as the arrivals: atomic add 0, sc0 = return old
                const unsigned int target = 8u * (unsigned int)(t + 1);
                unsigned int cur = 0, it = 0;
                do {
                    asm volatile("global_atomic_add %0, %1, %2, off sc0\n\t"
                                 "s_waitcnt vmcnt(0)"
                                 : "=v"(cur) : "v"(bar), "v"(0u) : "memory");
                    if (++it > (1u << 15)) break;
                } while (cur < target);
            }
            __syncthreads();
        }
    }
}

extern "C" void kernel_launch(void* const* d_in, const int* in_sizes, int n_in,
                              void* d_out, int out_size, void* d_ws, size_t ws_size,
                              hipStream_t stream)
{
    const float* x     = (const float*)d_in[0];
    const float* Wq    = (const float*)d_in[1];
    const float* bq    = (const float*)d_in[2];
    const float* Wk    = (const float*)d_in[3];
    const float* bk    = (const float*)d_in[4];
    const float* Wv    = (const float*)d_in[5];
    const float* bv    = (const float*)d_in[6];
    const float* Wo    = (const float*)d_in[7];
    const float* bo    = (const float*)d_in[8];
    const float* ln1g  = (const float*)d_in[9];
    const float* ln1b  = (const float*)d_in[10];
    const float* gruk  = (const float*)d_in[11];
    const float* grurk = (const float*)d_in[12];
    const float* grub  = (const float*)d_in[13];
    const float* Wd    = (const float*)d_in[14];
    const float* bd    = (const float*)d_in[15];
    const float* ln2g  = (const float*)d_in[16];
    const float* ln2b  = (const float*)d_in[17];
    float* out = (float*)d_out;

    char* base = (char*)d_ws;
    const size_t MB = 1024 * 1024;
    float*          Q0   = (float*)base;                      // 48 MB: q/k/v -> xp -> dense-out
    float*          R4   = (float*)(base + 48 * MB);          // 16 MB: x1
    unsigned short* S1   = (unsigned short*)(base + 64 * MB); // 8 MB: xb -> ctxb -> x1b -> goutb
    unsigned short* WT   = (unsigned short*)(base + 72 * MB); // 4 MB weights
    unsigned short* wqT  = WT;
    unsigned short* wkT  = WT + 256 * 1024;
    unsigned short* wvT  = WT + 512 * 1024;
    unsigned short* woT  = WT + 768 * 1024;
    unsigned short* gkT  = WT + 1024 * 1024;    // 1536x512
    unsigned short* wdT  = WT + 1792 * 1024;
    unsigned short* hbuf = (unsigned short*)(base + 76 * MB); // 2*16*512 bf16 = 32 KB
    unsigned int*   bar  = (unsigned int*)(base + 76 * MB + 64 * 1024);
    unsigned int*   ctl  = (unsigned int*)(base + 76 * MB + 64 * 1024 + 128);

    float* q = Q0;
    float* k = Q0 + (size_t)4 * MB;
    float* v = Q0 + (size_t)8 * MB;
    float* xpbuf = Q0;
    float* dout  = Q0;

    const dim3 blk(256);
    const dim3 g512(8192 / 128, 512 / 128);
    const dim3 g1536(8192 / 128, 1536 / 128);

    f2bf_kernel<<<dim3(4096), blk, 0, stream>>>(x, S1);
    transpose_bf16<<<dim3(16, 16), blk, 0, stream>>>(Wq, wqT, 512, 512);
    transpose_bf16<<<dim3(16, 16), blk, 0, stream>>>(Wk, wkT, 512, 512);
    transpose_bf16<<<dim3(16, 16), blk, 0, stream>>>(Wv, wvT, 512, 512);
    transpose_bf16<<<dim3(16, 16), blk, 0, stream>>>(Wo, woT, 512, 512);
    transpose_bf16<<<dim3(48, 16), blk, 0, stream>>>(gruk, gkT, 512, 1536);
    transpose_bf16<<<dim3(16, 16), blk, 0, stream>>>(Wd, wdT, 512, 512);
    gemm_bf16<<<g512, blk, 0, stream>>>(S1, wqT, bq, nullptr, q, 8192, 512, 512);
    gemm_bf16<<<g512, blk, 0, stream>>>(S1, wkT, bk, nullptr, k, 8192, 512, 512);
    gemm_bf16<<<g512, blk, 0, stream>>>(S1, wvT, bv, nullptr, v, 8192, 512, 512);
    attn_f32<<<dim3(1024), blk, 0, stream>>>(q, k, v, S1);
    gemm_bf16<<<g512, blk, 0, stream>>>(S1, woT, bo, x, R4, 8192, 512, 512);
    ln_f32<<<dim3(2048), blk, 0, stream>>>(R4, R4, ln1g, ln1b, S1);
    gemm_bf16<<<g1536, blk, 0, stream>>>(S1, gkT, grub, nullptr, xpbuf, 8192, 1536, 512);
    // persistent GRU (XCD-pinned)
    hipMemsetAsync(hbuf, 0, 2 * 16 * 512 * sizeof(unsigned short), stream);
    hipMemsetAsync(bar, 0, 512, stream);   // covers bar + ctl
    gru_persist<<<dim3(GRID_WGS), blk, 0, stream>>>(grurk, xpbuf, grub + 1536, hbuf, S1, bar, ctl);
    gemm_bf16<<<g512, blk, 0, stream>>>(S1, wdT, bd, R4, dout, 8192, 512, 512);
    ln_f32<<<dim3(2048), blk, 0, stream>>>(dout, out, ln2g, ln2b, nullptr);
}